// Round 1
// baseline (168.016 us; speedup 1.0000x reference)
//
#include <hip/hip_runtime.h>
#include <cstdint>
#include <cstddef>
#include <math.h>

// ---------------------------------------------------------------------------
// RandomCutoff: out = where(mask, log(f64 eps), x), x: (16, 25600, 256) f32.
// Mask is generated from jax.random with FIXED seed 42 -> input-independent.
// We reproduce JAX's threefry2x32 PRNG exactly on-device.
//
// PARTITIONABLE=1 -> jax_threefry_partitionable=True semantics (default in
// modern JAX): fold-like split, bits = enc(key,(hi,lo)).a ^ .b.
// PARTITIONABLE=0 -> legacy iota-halves semantics. Flip if mask mismatches.
// ---------------------------------------------------------------------------
#define PARTITIONABLE 1

#define C_TOT 16
#define C_MASKED 13
#define T_TOT 25600
#define F_TOT 256
#define NB 256          // T / 100 time blocks
#define TSTEP 100

static constexpr float LOG_EPS = -36.04365338911715f; // float32(log(f64 eps))

struct U2 { unsigned a, b; };

__host__ __device__ constexpr unsigned rotl_(unsigned x, int d) {
  return (x << d) | (x >> (32 - d));
}

// Threefry-2x32, 20 rounds, exactly as JAX's reference implementation.
__host__ __device__ constexpr U2 tf(unsigned k0, unsigned k1, unsigned x0, unsigned x1) {
  const unsigned ks2 = k0 ^ k1 ^ 0x1BD11BDAu;
  x0 += k0; x1 += k1;
  x0 += x1; x1 = rotl_(x1,13) ^ x0;
  x0 += x1; x1 = rotl_(x1,15) ^ x0;
  x0 += x1; x1 = rotl_(x1,26) ^ x0;
  x0 += x1; x1 = rotl_(x1, 6) ^ x0;
  x0 += k1; x1 += ks2 + 1u;
  x0 += x1; x1 = rotl_(x1,17) ^ x0;
  x0 += x1; x1 = rotl_(x1,29) ^ x0;
  x0 += x1; x1 = rotl_(x1,16) ^ x0;
  x0 += x1; x1 = rotl_(x1,24) ^ x0;
  x0 += ks2; x1 += k0 + 2u;
  x0 += x1; x1 = rotl_(x1,13) ^ x0;
  x0 += x1; x1 = rotl_(x1,15) ^ x0;
  x0 += x1; x1 = rotl_(x1,26) ^ x0;
  x0 += x1; x1 = rotl_(x1, 6) ^ x0;
  x0 += k0; x1 += k1 + 3u;
  x0 += x1; x1 = rotl_(x1,17) ^ x0;
  x0 += x1; x1 = rotl_(x1,29) ^ x0;
  x0 += x1; x1 = rotl_(x1,16) ^ x0;
  x0 += x1; x1 = rotl_(x1,24) ^ x0;
  x0 += k1; x1 += ks2 + 4u;
  x0 += x1; x1 = rotl_(x1,13) ^ x0;
  x0 += x1; x1 = rotl_(x1,15) ^ x0;
  x0 += x1; x1 = rotl_(x1,26) ^ x0;
  x0 += x1; x1 = rotl_(x1, 6) ^ x0;
  x0 += ks2; x1 += k0 + 5u;
  return U2{x0, x1};
}

// ---- compile-time key tree (seed 42 -> key data (0,42)) -------------------
#if PARTITIONABLE
// split(key): newkey_i = enc(key, (0, i)); n=2 -> kcoin=i0, kmask=i1
constexpr U2 KCOIN = tf(0u, 42u, 0u, 0u);
constexpr U2 KMASK = tf(0u, 42u, 0u, 1u);
// split(kmask, 4): k_i = enc(kmask, (0, i))
constexpr U2 K1 = tf(KMASK.a, KMASK.b, 0u, 0u);
constexpr U2 K2 = tf(KMASK.a, KMASK.b, 0u, 1u);
constexpr U2 K3 = tf(KMASK.a, KMASK.b, 0u, 2u);
constexpr U2 K4 = tf(KMASK.a, KMASK.b, 0u, 3u);
constexpr U2 CE = tf(KCOIN.a, KCOIN.b, 0u, 0u);
constexpr unsigned COIN_BITS = CE.a ^ CE.b;
#else
// legacy split(key): counts iota(4) -> pairs (0,2),(1,3); out=[a02,a13,b02,b13]
constexpr U2 E02 = tf(0u, 42u, 0u, 2u);
constexpr U2 E13 = tf(0u, 42u, 1u, 3u);
constexpr unsigned KCOIN_A = E02.a, KCOIN_B = E13.a;
constexpr unsigned KMASK_A = E02.b, KMASK_B = E13.b;
// split(kmask,4): counts iota(8) -> pairs (0,4),(1,5),(2,6),(3,7)
constexpr U2 S04 = tf(KMASK_A, KMASK_B, 0u, 4u);
constexpr U2 S15 = tf(KMASK_A, KMASK_B, 1u, 5u);
constexpr U2 S26 = tf(KMASK_A, KMASK_B, 2u, 6u);
constexpr U2 S37 = tf(KMASK_A, KMASK_B, 3u, 7u);
constexpr U2 K1 = U2{S04.a, S15.a};
constexpr U2 K2 = U2{S26.a, S37.a};
constexpr U2 K3 = U2{S04.b, S15.b};
constexpr U2 K4 = U2{S26.b, S37.b};
// scalar random_bits: odd-size pad -> enc(kcoin,(0,0)).a
constexpr unsigned COIN_BITS = tf(KCOIN_A, KCOIN_B, 0u, 0u).a;
#endif
// uniform() <= 0.5  <=>  mantissa bits (bits>>9) <= 2^22  (exact, integer)
constexpr bool APPLY = (COIN_BITS >> 9) <= 4194304u;

// uniform [0,1): bitcast((bits>>9)|0x3f800000) - 1
__device__ __forceinline__ float u01(unsigned bits) {
  return __uint_as_float((bits >> 9) | 0x3f800000u) - 1.0f;
}

// Per (c, time-block) mask parameters: j = c*256 + b, j in [0, 3328)
__device__ __forceinline__ void mask_params(int j, int& ts, int& te, int& fs, int& fe) {
  const unsigned uj = (unsigned)j;
  unsigned h, l, bits;
#if PARTITIONABLE
  U2 e;
  // tlen = randint(k1,(13,256),0,35): bits shape (2,13,256); hi at j, lo at 3328+j
  e = tf(K1.a, K1.b, 0u, uj);          h = e.a ^ e.b;
  e = tf(K1.a, K1.b, 0u, uj + 3328u);  l = e.a ^ e.b;
  const unsigned tl = ((h % 35u) * 11u + (l % 35u)) % 35u; // mult=(2^16%35)^2%35=11
  // tstart = floor(uniform(k2) * (100 - tlen))
  e = tf(K2.a, K2.b, 0u, uj);          bits = e.a ^ e.b;
  const int tstart = (int)floorf(u01(bits) * (float)(TSTEP - (int)tl));
  // flen = randint(k3,(13,256),0,30)
  e = tf(K3.a, K3.b, 0u, uj);          h = e.a ^ e.b;
  e = tf(K3.a, K3.b, 0u, uj + 3328u);  l = e.a ^ e.b;
  const unsigned fl = ((h % 30u) * 16u + (l % 30u)) % 30u; // mult=(2^16%30)^2%30=16
  // fstart = floor(uniform(k4) * (256 - flen))
  e = tf(K4.a, K4.b, 0u, uj);          bits = e.a ^ e.b;
  const int fstart = (int)floorf(u01(bits) * (float)(F_TOT - (int)fl));
#else
  // legacy: counts iota(n), halves paired (i, i+n/2)
  U2 e = tf(K1.a, K1.b, uj, uj + 3328u);       // randint bits, size 6656
  h = e.a; l = e.b;
  const unsigned tl = ((h % 35u) * 11u + (l % 35u)) % 35u;
  bits = (j < 1664) ? tf(K2.a, K2.b, uj, uj + 1664u).a
                    : tf(K2.a, K2.b, uj - 1664u, uj).b;  // uniform bits, size 3328
  const int tstart = (int)floorf(u01(bits) * (float)(TSTEP - (int)tl));
  e = tf(K3.a, K3.b, uj, uj + 3328u);
  h = e.a; l = e.b;
  const unsigned fl = ((h % 30u) * 16u + (l % 30u)) % 30u;
  bits = (j < 1664) ? tf(K4.a, K4.b, uj, uj + 1664u).a
                    : tf(K4.a, K4.b, uj - 1664u, uj).b;
  const int fstart = (int)floorf(u01(bits) * (float)(F_TOT - (int)fl));
#endif
  ts = tstart; te = tstart + (int)tl;
  fs = fstart; fe = fstart + (int)fl;
}

// One block per (c, time-block) chunk: 100 rows x 256 f = 25600 floats.
// Streaming float4 copy with wave-uniform mask branch (64 f4 = one t-row).
__global__ void __launch_bounds__(256)
speca_kernel(const float* __restrict__ x, float* __restrict__ y) {
  const int bid = blockIdx.x;
  const int c = bid >> 8;          // 0..15
  const int b = bid & 255;         // 0..255
  const size_t base = ((size_t)c * T_TOT + (size_t)b * TSTEP) * F_TOT;
  const float4* __restrict__ in4 = (const float4*)(x + base);
  float4* __restrict__ o4 = (float4*)(y + base);

  int ts = 0, te = -1, fs = 0, fe = -1;
  if (APPLY && c < C_MASKED) {
    mask_params((c << 8) | b, ts, te, fs, fe);
  }

  for (int i = (int)threadIdx.x; i < (TSTEP * F_TOT) / 4; i += 256) {
    float4 v = in4[i];
    const int r = i >> 6;                    // local t within chunk (0..99)
    if (r >= ts && r < te) {                 // wave-uniform
      const int f0 = (i & 63) << 2;
      if (f0     >= fs && f0     < fe) v.x = LOG_EPS;
      if (f0 + 1 >= fs && f0 + 1 < fe) v.y = LOG_EPS;
      if (f0 + 2 >= fs && f0 + 2 < fe) v.z = LOG_EPS;
      if (f0 + 3 >= fs && f0 + 3 < fe) v.w = LOG_EPS;
    }
    o4[i] = v;
  }
}

extern "C" void kernel_launch(void* const* d_in, const int* in_sizes, int n_in,
                              void* d_out, int out_size, void* d_ws, size_t ws_size,
                              hipStream_t stream) {
  const float* x = (const float*)d_in[0];
  float* y = (float*)d_out;
  // 16 channels * 256 time-blocks = 4096 blocks
  hipLaunchKernelGGL(speca_kernel, dim3(C_TOT * NB), dim3(256), 0, stream, x, y);
}

// Round 2
// 152.073 us; speedup vs baseline: 1.1048x; 1.1048x over previous
//
#include <hip/hip_runtime.h>
#include <cstdint>
#include <cstddef>
#include <math.h>

// ---------------------------------------------------------------------------
// RandomCutoff: out = where(mask, log(f64 eps), x), x: (16, 25600, 256) f32.
// Mask comes from jax.random with FIXED seed 42 -> input-independent; we
// reproduce JAX's threefry2x32 (partitionable mode) exactly on-device.
// R1: nontemporal load/store (pure stream, zero reuse) + compile-time
//     trip count fully unrolled for deeper VMEM pipelining.
// ---------------------------------------------------------------------------

#define C_TOT 16
#define C_MASKED 13
#define T_TOT 25600
#define F_TOT 256
#define NB 256          // T / 100 time blocks
#define TSTEP 100

static constexpr float LOG_EPS = -36.04365338911715f; // float32(log(f64 eps))

typedef float f32x4 __attribute__((ext_vector_type(4)));

struct U2 { unsigned a, b; };

__host__ __device__ constexpr unsigned rotl_(unsigned x, int d) {
  return (x << d) | (x >> (32 - d));
}

// Threefry-2x32, 20 rounds, exactly as JAX's reference implementation.
__host__ __device__ constexpr U2 tf(unsigned k0, unsigned k1, unsigned x0, unsigned x1) {
  const unsigned ks2 = k0 ^ k1 ^ 0x1BD11BDAu;
  x0 += k0; x1 += k1;
  x0 += x1; x1 = rotl_(x1,13) ^ x0;
  x0 += x1; x1 = rotl_(x1,15) ^ x0;
  x0 += x1; x1 = rotl_(x1,26) ^ x0;
  x0 += x1; x1 = rotl_(x1, 6) ^ x0;
  x0 += k1; x1 += ks2 + 1u;
  x0 += x1; x1 = rotl_(x1,17) ^ x0;
  x0 += x1; x1 = rotl_(x1,29) ^ x0;
  x0 += x1; x1 = rotl_(x1,16) ^ x0;
  x0 += x1; x1 = rotl_(x1,24) ^ x0;
  x0 += ks2; x1 += k0 + 2u;
  x0 += x1; x1 = rotl_(x1,13) ^ x0;
  x0 += x1; x1 = rotl_(x1,15) ^ x0;
  x0 += x1; x1 = rotl_(x1,26) ^ x0;
  x0 += x1; x1 = rotl_(x1, 6) ^ x0;
  x0 += k0; x1 += k1 + 3u;
  x0 += x1; x1 = rotl_(x1,17) ^ x0;
  x0 += x1; x1 = rotl_(x1,29) ^ x0;
  x0 += x1; x1 = rotl_(x1,16) ^ x0;
  x0 += x1; x1 = rotl_(x1,24) ^ x0;
  x0 += k1; x1 += ks2 + 4u;
  x0 += x1; x1 = rotl_(x1,13) ^ x0;
  x0 += x1; x1 = rotl_(x1,15) ^ x0;
  x0 += x1; x1 = rotl_(x1,26) ^ x0;
  x0 += x1; x1 = rotl_(x1, 6) ^ x0;
  x0 += ks2; x1 += k0 + 5u;
  return U2{x0, x1};
}

// ---- compile-time key tree (seed 42 -> key data (0,42)), partitionable ----
constexpr U2 KCOIN = tf(0u, 42u, 0u, 0u);
constexpr U2 KMASK = tf(0u, 42u, 0u, 1u);
constexpr U2 K1 = tf(KMASK.a, KMASK.b, 0u, 0u);
constexpr U2 K2 = tf(KMASK.a, KMASK.b, 0u, 1u);
constexpr U2 K3 = tf(KMASK.a, KMASK.b, 0u, 2u);
constexpr U2 K4 = tf(KMASK.a, KMASK.b, 0u, 3u);
constexpr U2 CE = tf(KCOIN.a, KCOIN.b, 0u, 0u);
constexpr unsigned COIN_BITS = CE.a ^ CE.b;
// uniform() <= 0.5  <=>  mantissa bits (bits>>9) <= 2^22  (exact, integer)
constexpr bool APPLY = (COIN_BITS >> 9) <= 4194304u;

// uniform [0,1): bitcast((bits>>9)|0x3f800000) - 1
__device__ __forceinline__ float u01(unsigned bits) {
  return __uint_as_float((bits >> 9) | 0x3f800000u) - 1.0f;
}

// Per (c, time-block) mask parameters: j = c*256 + b, j in [0, 3328)
__device__ __forceinline__ void mask_params(int j, int& ts, int& te, int& fs, int& fe) {
  const unsigned uj = (unsigned)j;
  unsigned h, l, bits;
  U2 e;
  // tlen = randint(k1,(13,256),0,35): bits shape (2,13,256); hi at j, lo at 3328+j
  e = tf(K1.a, K1.b, 0u, uj);          h = e.a ^ e.b;
  e = tf(K1.a, K1.b, 0u, uj + 3328u);  l = e.a ^ e.b;
  const unsigned tl = ((h % 35u) * 11u + (l % 35u)) % 35u; // mult=(2^16%35)^2%35=11
  // tstart = floor(uniform(k2) * (100 - tlen))
  e = tf(K2.a, K2.b, 0u, uj);          bits = e.a ^ e.b;
  const int tstart = (int)floorf(u01(bits) * (float)(TSTEP - (int)tl));
  // flen = randint(k3,(13,256),0,30)
  e = tf(K3.a, K3.b, 0u, uj);          h = e.a ^ e.b;
  e = tf(K3.a, K3.b, 0u, uj + 3328u);  l = e.a ^ e.b;
  const unsigned fl = ((h % 30u) * 16u + (l % 30u)) % 30u; // mult=(2^16%30)^2%30=16
  // fstart = floor(uniform(k4) * (256 - flen))
  e = tf(K4.a, K4.b, 0u, uj);          bits = e.a ^ e.b;
  const int fstart = (int)floorf(u01(bits) * (float)(F_TOT - (int)fl));
  ts = tstart; te = tstart + (int)tl;
  fs = fstart; fe = fstart + (int)fl;
}

// One block per (c, time-block) chunk: 100 rows x 256 f = 25600 floats
// = 6400 float4 = 25 iterations of 256 threads. Trip count is compile-time;
// fully unrolled so the compiler batches global_load_dwordx4 issues.
// Nontemporal hints: pure stream, zero reuse (input 419 MB > L3).
__global__ void __launch_bounds__(256)
speca_kernel(const float* __restrict__ x, float* __restrict__ y) {
  const int bid = blockIdx.x;
  const int c = bid >> 8;          // 0..15
  const int b = bid & 255;         // 0..255
  const size_t base = ((size_t)c * T_TOT + (size_t)b * TSTEP) * F_TOT;
  const f32x4* __restrict__ in4 = (const f32x4*)(x + base);
  f32x4* __restrict__ o4 = (f32x4*)(y + base);

  int ts = 0, te = -1, fs = 0, fe = -1;
  if (APPLY && c < C_MASKED) {
    mask_params((c << 8) | b, ts, te, fs, fe);
  }

  const int tid = (int)threadIdx.x;
#pragma unroll
  for (int k = 0; k < (TSTEP * F_TOT) / 4 / 256; ++k) {   // 25
    const int i = k * 256 + tid;
    f32x4 v = __builtin_nontemporal_load(&in4[i]);
    const int r = i >> 6;                    // local t within chunk (0..99)
    if (r >= ts && r < te) {                 // wave-uniform (64 f4 = one row)
      const int f0 = (i & 63) << 2;
      if (f0     >= fs && f0     < fe) v[0] = LOG_EPS;
      if (f0 + 1 >= fs && f0 + 1 < fe) v[1] = LOG_EPS;
      if (f0 + 2 >= fs && f0 + 2 < fe) v[2] = LOG_EPS;
      if (f0 + 3 >= fs && f0 + 3 < fe) v[3] = LOG_EPS;
    }
    __builtin_nontemporal_store(v, &o4[i]);
  }
}

extern "C" void kernel_launch(void* const* d_in, const int* in_sizes, int n_in,
                              void* d_out, int out_size, void* d_ws, size_t ws_size,
                              hipStream_t stream) {
  const float* x = (const float*)d_in[0];
  float* y = (float*)d_out;
  // 16 channels * 256 time-blocks = 4096 blocks
  hipLaunchKernelGGL(speca_kernel, dim3(C_TOT * NB), dim3(256), 0, stream, x, y);
}